// Round 2
// baseline (208.484 us; speedup 1.0000x reference)
//
#include <hip/hip_runtime.h>
#include <stdint.h>

#define NCH   30                  // channels per cell (cell = 120 B)
#define TPB   256
#define CPB   256                 // cells per block
#define WORDS (CPB * NCH)         // 7680 floats per array tile
#define TOTW  (2 * WORDS)         // 15360 floats staged per block
#define NF4   (TOTW / 4)          // 3840 float4 chunks
#define ITERS (NF4 / TPB)         // 15 global_load_lds per thread

__device__ __forceinline__ float iou_f(float x1, float y1, float w1, float h1,
                                       float x2, float y2, float w2, float h2) {
    float l1 = x1 - 0.5f * w1, r1 = x1 + 0.5f * w1;
    float t1 = y1 - 0.5f * h1, b1 = y1 + 0.5f * h1;
    float l2 = x2 - 0.5f * w2, r2 = x2 + 0.5f * w2;
    float t2 = y2 - 0.5f * h2, b2 = y2 + 0.5f * h2;
    float in_h = fminf(b1, b2) - fmaxf(t1, t2);
    float in_w = fminf(r1, r2) - fmaxf(l1, l2);
    float inter = (in_h < 0.f || in_w < 0.f) ? 0.f : in_h * in_w;
    float a1 = (b1 - t1) * (r1 - l1);
    float a2 = (b2 - t2) * (r2 - l2);
    return inter / (a1 + a2 - inter);
}

// Block-tile LDS staging: each block stages 256 cells of pred+labels into LDS
// via width-16 global_load_lds (fully coalesced, 1 KB/wave/instr, no VGPR
// round-trip), then computes per-cell losses from LDS.
__global__ __launch_bounds__(TPB) void yolo_partial(const float* __restrict__ pred,
                                                    const float* __restrict__ lab,
                                                    float* __restrict__ partial,
                                                    int n_cells) {
    __shared__ float s[TOTW];            // [0..WORDS) = pred tile, [WORDS..) = lab tile
    __shared__ float red[5][TPB / 64];

    const int tid = threadIdx.x;
    const int base_cell = blockIdx.x * CPB;
    const size_t base_word = (size_t)base_cell * NCH;
    const int cells_here = min(CPB, n_cells - base_cell);

    if (cells_here == CPB) {
        // Fast path: full tile. LDS dest is linear (wave-uniform base + lane*16,
        // required by global_load_lds); global src address is per-lane and may
        // legally split between the pred and lab streams mid-wave.
#pragma unroll
        for (int it = 0; it < ITERS; ++it) {
            const int idx = it * TPB + tid;               // float4 index in combined stream
            const float* src = (idx < WORDS / 4)
                ? (pred + base_word + (size_t)idx * 4)
                : (lab  + base_word + (size_t)(idx - WORDS / 4) * 4);
            __builtin_amdgcn_global_load_lds(
                (const __attribute__((address_space(1))) uint32_t*)src,
                (__attribute__((address_space(3))) uint32_t*)(s + idx * 4),
                16, 0, 0);
        }
    } else {
        // Tail block (never taken for 802816 cells, kept for safety).
        const int nw = cells_here * NCH;
        for (int w = tid; w < nw; w += TPB) {
            s[w]         = pred[base_word + w];
            s[WORDS + w] = lab [base_word + w];
        }
    }
    __syncthreads();   // emits s_waitcnt vmcnt(0) -> global_load_lds data landed

    float v0 = 0.f, v1 = 0.f, v2 = 0.f, v3 = 0.f, v4 = 0.f;

    if (tid < cells_here) {
        const float* pp = s + tid * NCH;            // this thread's pred cell (LDS)
        const float* lp = s + WORDS + tid * NCH;    // this thread's label cell (LDS)

        const float2 l01 = *(const float2*)(lp);    // ch0 (mask), ch1 (gx)
        const float mask = l01.x;

        if (mask != 0.f) {
            const float2 l23 = *(const float2*)(lp + 2); // gy, gw
            const float2 l45 = *(const float2*)(lp + 4); // gh, -
            const float gx = l01.y, gy = l23.x, gw = l23.y, gh = l45.x;

            const float2 p01 = *(const float2*)(pp);     // -, b1x
            const float2 p23 = *(const float2*)(pp + 2); // b1y, b1w
            const float2 p45 = *(const float2*)(pp + 4); // b1h, -
            const float2 p67 = *(const float2*)(pp + 6); // b2x, b2y
            const float2 p89 = *(const float2*)(pp + 8); // b2w, b2h

            const float i1 = iou_f(p01.y, p23.x, p23.y, p45.x, gx, gy, gw, gh);
            const float i2 = iou_f(p67.x, p67.y, p89.x, p89.y, gx, gy, gw, gh);
            const bool best = (i1 >= i2);
            const float sx = best ? p01.y : p67.x;
            const float sy = best ? p23.x : p67.y;
            const float sw = best ? p23.y : p89.x;
            const float sh = best ? p45.x : p89.y;
            const float imax = best ? i1 : i2;
            const float imin = best ? i2 : i1;

            const float center = 5.f * ((sx - gx) * (sx - gx) + (sy - gy) * (sy - gy));
            const float dw = sqrtf(sw) - sqrtf(gw);
            const float dh = sqrtf(sh) - sqrtf(gh);
            const float wh = 5.f * (dw * dw + dh * dh);

            float cls = 0.f;
#pragma unroll
            for (int k = 0; k < 10; ++k) {               // channels 10..29
                const float2 pd = *(const float2*)(pp + 10 + 2 * k);
                const float2 ld = *(const float2*)(lp + 10 + 2 * k);
                const float dx = pd.x - ld.x;
                const float dy = pd.y - ld.y;
                cls += dx * dx + dy * dy;
            }

            v0 = center * mask;
            v1 = wh * mask;
            v2 = imax * mask;
            v3 = imin * mask;
            v4 = cls * mask;
        }
    }

    // ---- Wave (64-lane) shuffle reduction ----
#pragma unroll
    for (int off = 32; off > 0; off >>= 1) {
        v0 += __shfl_down(v0, off);
        v1 += __shfl_down(v1, off);
        v2 += __shfl_down(v2, off);
        v3 += __shfl_down(v3, off);
        v4 += __shfl_down(v4, off);
    }

    const int wave = tid >> 6;
    const int lane = tid & 63;
    if (lane == 0) {
        red[0][wave] = v0;
        red[1][wave] = v1;
        red[2][wave] = v2;
        red[3][wave] = v3;
        red[4][wave] = v4;
    }
    __syncthreads();

    if (tid < 5) {
        float sacc = 0.f;
#pragma unroll
        for (int w = 0; w < TPB / 64; ++w) sacc += red[tid][w];
        partial[(size_t)blockIdx.x * 5 + tid] = sacc;
    }
}

// Reduce n_blocks x 5 partials -> out[0..4]. One block.
__global__ __launch_bounds__(256) void final_reduce(const float* __restrict__ partial,
                                                    float* __restrict__ out,
                                                    int n_blocks) {
    __shared__ float red[5][4];
    const int tid = threadIdx.x;
    float v0 = 0.f, v1 = 0.f, v2 = 0.f, v3 = 0.f, v4 = 0.f;
    for (int b = tid; b < n_blocks; b += 256) {
        const float* p = partial + (size_t)b * 5;
        v0 += p[0]; v1 += p[1]; v2 += p[2]; v3 += p[3]; v4 += p[4];
    }
#pragma unroll
    for (int off = 32; off > 0; off >>= 1) {
        v0 += __shfl_down(v0, off);
        v1 += __shfl_down(v1, off);
        v2 += __shfl_down(v2, off);
        v3 += __shfl_down(v3, off);
        v4 += __shfl_down(v4, off);
    }
    const int wave = tid >> 6;
    const int lane = tid & 63;
    if (lane == 0) {
        red[0][wave] = v0;
        red[1][wave] = v1;
        red[2][wave] = v2;
        red[3][wave] = v3;
        red[4][wave] = v4;
    }
    __syncthreads();
    if (tid < 5) {
        float sacc = 0.f;
#pragma unroll
        for (int w = 0; w < 4; ++w) sacc += red[tid][w];
        out[tid] = sacc;
    }
}

extern "C" void kernel_launch(void* const* d_in, const int* in_sizes, int n_in,
                              void* d_out, int out_size, void* d_ws, size_t ws_size,
                              hipStream_t stream) {
    const float* pred = (const float*)d_in[0];
    const float* lab  = (const float*)d_in[1];
    float* out = (float*)d_out;
    float* partial = (float*)d_ws;                 // 3136*5*4 = 62,720 B

    const int n_cells = in_sizes[0] / NCH;         // 802816
    const int grid = (n_cells + CPB - 1) / CPB;    // 3136

    hipLaunchKernelGGL(yolo_partial, dim3(grid), dim3(TPB), 0, stream,
                       pred, lab, partial, n_cells);
    hipLaunchKernelGGL(final_reduce, dim3(1), dim3(256), 0, stream,
                       partial, out, grid);
}

// Round 3
// 208.310 us; speedup vs baseline: 1.0008x; 1.0008x over previous
//
#include <hip/hip_runtime.h>
#include <stdint.h>

#define NCH    30                  // channels per cell (cell = 120 B)
#define TPW    64                  // one wave per block
#define TILE   64                  // cells per tile (one per lane)
#define TWORDS (TILE * NCH)        // 1920 floats per array per tile
#define TF4    (2 * TWORDS / 4)    // 960 float4 chunks per tile (pred+lab)
#define LOADS  (TF4 / TPW)         // 15 global_load_lds per lane per tile
#define NBLK   1280                // 5 blocks/CU * 256 CUs

__device__ __forceinline__ float iou_f(float x1, float y1, float w1, float h1,
                                       float x2, float y2, float w2, float h2) {
    float l1 = x1 - 0.5f * w1, r1 = x1 + 0.5f * w1;
    float t1 = y1 - 0.5f * h1, b1 = y1 + 0.5f * h1;
    float l2 = x2 - 0.5f * w2, r2 = x2 + 0.5f * w2;
    float t2 = y2 - 0.5f * h2, b2 = y2 + 0.5f * h2;
    float in_h = fminf(b1, b2) - fmaxf(t1, t2);
    float in_w = fminf(r1, r2) - fmaxf(l1, l2);
    float inter = (in_h < 0.f || in_w < 0.f) ? 0.f : in_h * in_w;
    float a1 = (b1 - t1) * (r1 - l1);
    float a2 = (b2 - t2) * (r2 - l2);
    return inter / (a1 + a2 - inter);
}

// Stage one 64-cell tile (pred+lab, 15360 B) into an LDS buffer with 15
// width-16 global_load_lds. LDS dest is linear in idx (= wave-uniform base +
// lane*16 per instruction, as required); global src is per-lane and may split
// between the pred and lab streams mid-wave.
__device__ __forceinline__ void stage_tile(const float* __restrict__ pred,
                                           const float* __restrict__ lab,
                                           float* __restrict__ buf,
                                           int tile, int lane) {
    const size_t base = (size_t)tile * TWORDS;
#pragma unroll
    for (int i = 0; i < LOADS; ++i) {
        const int idx = i * TPW + lane;            // float4 index in [0, 960)
        const float* src = (idx < TWORDS / 4)
            ? (pred + base + (size_t)idx * 4)
            : (lab  + base + (size_t)(idx - TWORDS / 4) * 4);
        __builtin_amdgcn_global_load_lds(
            (const __attribute__((address_space(1))) uint32_t*)src,
            (__attribute__((address_space(3))) uint32_t*)(buf + idx * 4),
            16, 0, 0);
    }
}

// Compute the 5 loss terms for the cell held in LDS at pp/lp, accumulate.
__device__ __forceinline__ void cell_loss(const float* __restrict__ pp,
                                          const float* __restrict__ lp,
                                          float& v0, float& v1, float& v2,
                                          float& v3, float& v4) {
    const float2 l01 = *(const float2*)(lp);        // mask, gx
    const float mask = l01.x;
    if (mask == 0.f) return;

    const float2 l23 = *(const float2*)(lp + 2);    // gy, gw
    const float2 l45 = *(const float2*)(lp + 4);    // gh, -
    const float gx = l01.y, gy = l23.x, gw = l23.y, gh = l45.x;

    const float2 p01 = *(const float2*)(pp);        // -, b1x
    const float2 p23 = *(const float2*)(pp + 2);    // b1y, b1w
    const float2 p45 = *(const float2*)(pp + 4);    // b1h, -
    const float2 p67 = *(const float2*)(pp + 6);    // b2x, b2y
    const float2 p89 = *(const float2*)(pp + 8);    // b2w, b2h

    const float i1 = iou_f(p01.y, p23.x, p23.y, p45.x, gx, gy, gw, gh);
    const float i2 = iou_f(p67.x, p67.y, p89.x, p89.y, gx, gy, gw, gh);
    const bool best = (i1 >= i2);
    const float sx = best ? p01.y : p67.x;
    const float sy = best ? p23.x : p67.y;
    const float sw = best ? p23.y : p89.x;
    const float sh = best ? p45.x : p89.y;
    const float imax = best ? i1 : i2;
    const float imin = best ? i2 : i1;

    const float center = 5.f * ((sx - gx) * (sx - gx) + (sy - gy) * (sy - gy));
    const float dw = sqrtf(sw) - sqrtf(gw);
    const float dh = sqrtf(sh) - sqrtf(gh);
    const float wh = 5.f * (dw * dw + dh * dh);

    float cls = 0.f;
#pragma unroll
    for (int k = 0; k < 10; ++k) {                  // channels 10..29
        const float2 pd = *(const float2*)(pp + 10 + 2 * k);
        const float2 ld = *(const float2*)(lp + 10 + 2 * k);
        const float dx = pd.x - ld.x;
        const float dy = pd.y - ld.y;
        cls += dx * dx + dy * dy;
    }

    v0 += center * mask;
    v1 += wh * mask;
    v2 += imax * mask;
    v3 += imin * mask;
    v4 += cls * mask;
}

// Persistent single-wave blocks. Each wave double-buffers 64-cell tiles in its
// private LDS region and uses counted per-wave vmcnt waits — loads never drain
// to 0 in the main loop, no __syncthreads anywhere.
__global__ __launch_bounds__(TPW) void yolo_partial(const float* __restrict__ pred,
                                                    const float* __restrict__ lab,
                                                    float* __restrict__ partial,
                                                    int n_cells) {
    __shared__ float s[4 * TWORDS];                 // 2 buffers x 3840 floats = 30720 B
    const int lane = threadIdx.x;
    const int bid = blockIdx.x;
    const int NB = gridDim.x;
    const int nt = n_cells / TILE;                  // 12544 full tiles

    float v0 = 0.f, v1 = 0.f, v2 = 0.f, v3 = 0.f, v4 = 0.f;

    float* A = s;
    float* B = s + 2 * TWORDS;

    if (bid < nt) {
        stage_tile(pred, lab, A, bid, lane);                   // 15 outstanding
        if (bid + NB < nt) stage_tile(pred, lab, B, bid + NB, lane); // 30 outstanding

        for (int t = bid; t < nt; t += NB) {
            const bool more  = (t + NB < nt);       // next tile staged in other buffer
            const bool more2 = (t + 2 * NB < nt);   // will prefetch into this buffer
            if (more) {
                // all but the newest 15 ops retired => current buffer complete,
                // next buffer's loads stay in flight across the compute
                asm volatile("s_waitcnt vmcnt(15)" ::: "memory");
            } else {
                asm volatile("s_waitcnt vmcnt(0)" ::: "memory");
            }
            __builtin_amdgcn_sched_barrier(0);

            cell_loss(A + lane * NCH, A + TWORDS + lane * NCH, v0, v1, v2, v3, v4);

            if (more2) {
                // ds_reads fully retired before their buffer is overwritten
                asm volatile("s_waitcnt lgkmcnt(0)" ::: "memory");
                __builtin_amdgcn_sched_barrier(0);
                stage_tile(pred, lab, A, t + 2 * NB, lane);
            }
            float* tmp = A; A = B; B = tmp;
        }
    }

    // Remainder cells (n_cells % 64) — direct from global. Never taken for
    // 802816 cells; kept for shape safety.
    const int rem_start = nt * TILE;
    if (bid == 0 && rem_start < n_cells) {
        for (int c = rem_start + lane; c < n_cells; c += TPW) {
            cell_loss(pred + (size_t)c * NCH, lab + (size_t)c * NCH,
                      v0, v1, v2, v3, v4);   // pointers are global; same math
        }
    }

    // ---- wave (64-lane) shuffle reduction, one wave per block ----
#pragma unroll
    for (int off = 32; off > 0; off >>= 1) {
        v0 += __shfl_down(v0, off);
        v1 += __shfl_down(v1, off);
        v2 += __shfl_down(v2, off);
        v3 += __shfl_down(v3, off);
        v4 += __shfl_down(v4, off);
    }
    if (lane == 0) {
        float* p = partial + (size_t)bid * 5;
        p[0] = v0; p[1] = v1; p[2] = v2; p[3] = v3; p[4] = v4;
    }
}

// Reduce n_blocks x 5 partials -> out[0..4]. One block.
__global__ __launch_bounds__(256) void final_reduce(const float* __restrict__ partial,
                                                    float* __restrict__ out,
                                                    int n_blocks) {
    __shared__ float red[5][4];
    const int tid = threadIdx.x;
    float v0 = 0.f, v1 = 0.f, v2 = 0.f, v3 = 0.f, v4 = 0.f;
    for (int b = tid; b < n_blocks; b += 256) {
        const float* p = partial + (size_t)b * 5;
        v0 += p[0]; v1 += p[1]; v2 += p[2]; v3 += p[3]; v4 += p[4];
    }
#pragma unroll
    for (int off = 32; off > 0; off >>= 1) {
        v0 += __shfl_down(v0, off);
        v1 += __shfl_down(v1, off);
        v2 += __shfl_down(v2, off);
        v3 += __shfl_down(v3, off);
        v4 += __shfl_down(v4, off);
    }
    const int wave = tid >> 6;
    const int lane = tid & 63;
    if (lane == 0) {
        red[0][wave] = v0;
        red[1][wave] = v1;
        red[2][wave] = v2;
        red[3][wave] = v3;
        red[4][wave] = v4;
    }
    __syncthreads();
    if (tid < 5) {
        float sacc = 0.f;
#pragma unroll
        for (int w = 0; w < 4; ++w) sacc += red[tid][w];
        out[tid] = sacc;
    }
}

extern "C" void kernel_launch(void* const* d_in, const int* in_sizes, int n_in,
                              void* d_out, int out_size, void* d_ws, size_t ws_size,
                              hipStream_t stream) {
    const float* pred = (const float*)d_in[0];
    const float* lab  = (const float*)d_in[1];
    float* out = (float*)d_out;
    float* partial = (float*)d_ws;                 // 1280*5*4 = 25,600 B

    const int n_cells = in_sizes[0] / NCH;         // 802816

    hipLaunchKernelGGL(yolo_partial, dim3(NBLK), dim3(TPW), 0, stream,
                       pred, lab, partial, n_cells);
    hipLaunchKernelGGL(final_reduce, dim3(1), dim3(256), 0, stream,
                       partial, out, NBLK);
}